// Round 6
// baseline (690.925 us; speedup 1.0000x reference)
//
#include <hip/hip_runtime.h>

typedef unsigned short u16;
typedef __bf16 bf16x8 __attribute__((ext_vector_type(8)));
typedef float f32x4 __attribute__((ext_vector_type(4)));
typedef u16 u16x4 __attribute__((ext_vector_type(4)));

#define SEQ 2048
#define NQKV 6144
#define HID 4096

__device__ inline u16 f2bf(float f) {
  union { float f; unsigned u; } x; x.f = f;
  unsigned r = x.u + 0x7fffu + ((x.u >> 16) & 1u);  // RNE
  return (u16)(r >> 16);
}
__device__ inline float bf2f(u16 u) {
  union { unsigned u; float f; } x; x.u = ((unsigned)u) << 16;
  return x.f;
}
__device__ inline f32x4 mfma16(bf16x8 a, bf16x8 b, f32x4 c) {
  return __builtin_amdgcn_mfma_f32_16x16x32_bf16(a, b, c, 0, 0, 0);
}
__device__ inline void gload16(const void* g, void* l) {
  __builtin_amdgcn_global_load_lds((const __attribute__((address_space(1))) void*)g,
                                   (__attribute__((address_space(3))) void*)l,
                                   16, 0, 0);
}

// ---------- fp32 -> bf16 contiguous convert ----------
__global__ __launch_bounds__(256) void conv_kernel(const float* __restrict__ in,
                                                   u16* __restrict__ out) {
  int i = (blockIdx.x * 256 + threadIdx.x) * 4;
  float4 v = *(const float4*)(in + i);
  u16x4 o;
  o[0] = f2bf(v.x); o[1] = f2bf(v.y); o[2] = f2bf(v.z); o[3] = f2bf(v.w);
  *(u16x4*)(out + i) = o;
}

// ---------- fp32 [R][C] -> bf16 [C][R] transpose-convert ----------
__global__ __launch_bounds__(256) void transconv_kernel(const float* __restrict__ in,
                                                        u16* __restrict__ out,
                                                        int R, int C) {
  __shared__ u16 tile[32][33];
  int c0 = blockIdx.x * 32, r0 = blockIdx.y * 32;
  int tx = threadIdx.x & 31, ty = threadIdx.x >> 5;
  for (int i = 0; i < 4; ++i)
    tile[ty + 8 * i][tx] = f2bf(in[(size_t)(r0 + ty + 8 * i) * C + c0 + tx]);
  __syncthreads();
  for (int i = 0; i < 4; ++i)
    out[(size_t)(c0 + ty + 8 * i) * R + r0 + tx] = tile[tx][ty + 8 * i];
}

// ---------- bf16 GEMM: A[M][K] x Bt[N][K] -> C[M][N] ----------
// 256x256/BK64 8-wave quadrant schedule (R5: took gemms off the critical
// path; see R4/R5 comments in history). Unchanged this round.
__device__ inline void store_out(u16* p, float v) { *p = f2bf(v); }
__device__ inline void store_out(float* p, float v) { *p = v; }

template <typename OutT>
__global__ __launch_bounds__(512, 2) void gemm_kernel(const u16* __restrict__ A,
                                                      const u16* __restrict__ Bt,
                                                      OutT* __restrict__ C,
                                                      int M, int N, int K, int nby) {
  __shared__ __align__(16) u16 As[2][256 * 64];
  __shared__ __align__(16) u16 Bs[2][256 * 64];
  int nwg = gridDim.x;                      // multiple of 8
  int bid = blockIdx.x;
  int s = (bid & 7) * (nwg >> 3) + (bid >> 3);   // XCD-contiguous, bijective
  int by = s % nby, bx = s / nby;
  int row0 = by * 256, col0 = bx * 256;
  int tid = threadIdx.x, w = tid >> 6, l = tid & 63;
  int wm = w >> 2, wn = w & 3;              // wave tile 128x64
  int lo = l & 15, hi = l >> 4;
  int lr = l >> 3;                          // staging: row within 8-row chunk
  int lc = (l & 7) ^ ((l >> 3) & 7);        // pre-swizzled source k-chunk
  const u16* Ab = A + (size_t)row0 * K;
  const u16* Bb = Bt + (size_t)col0 * K;
  int nkt = K >> 6;

  f32x4 acc[8][4] = {};

#define STAGE(tt, g)                                                          \
  { int ci = (g) * 8 + w;                                                     \
    gload16(Ab + (size_t)(ci * 8 + lr) * K + (tt) * 64 + lc * 8,              \
            &As[(tt) & 1][ci * 512]);                                         \
    gload16(Bb + (size_t)(ci * 8 + lr) * K + (tt) * 64 + lc * 8,              \
            &Bs[(tt) & 1][ci * 512]); }
#define RD_A(cur, qm, fm, kh, dst)                                            \
  { int r = wm * 128 + (qm) * 64 + (fm) * 16 + lo;                            \
    dst = *(const bf16x8*)&As[cur][r * 64 + ((((kh) * 4 + hi) ^ (r & 7)) * 8)]; }
#define RD_B(cur, qn, fn, kh, dst)                                            \
  { int r = wn * 64 + (qn) * 32 + (fn) * 16 + lo;                             \
    dst = *(const bf16x8*)&Bs[cur][r * 64 + ((((kh) * 4 + hi) ^ (r & 7)) * 8)]; }

  // prologue: stage tile 0 fully
  STAGE(0, 0); STAGE(0, 1); STAGE(0, 2); STAGE(0, 3);
  asm volatile("s_waitcnt vmcnt(0)" ::: "memory");
  __builtin_amdgcn_s_barrier();

  bf16x8 af[4][2], bfr[2][2];
  for (int t = 0; t < nkt; ++t) {
    int cur = t & 1;
    bool pf = (t + 1 < nkt);
    // ---- phase 0: quadrant (qm=0, qn=0); load A0, B0 ----
    for (int fm = 0; fm < 4; ++fm)
      for (int kh = 0; kh < 2; ++kh) RD_A(cur, 0, fm, kh, af[fm][kh]);
    for (int fn = 0; fn < 2; ++fn)
      for (int kh = 0; kh < 2; ++kh) RD_B(cur, 0, fn, kh, bfr[fn][kh]);
    if (pf) { STAGE(t + 1, 0); STAGE(t + 1, 1); }
    __builtin_amdgcn_s_barrier();
    __builtin_amdgcn_s_setprio(1);
    for (int fm = 0; fm < 4; ++fm)
      for (int fn = 0; fn < 2; ++fn)
        for (int kh = 0; kh < 2; ++kh)
          acc[fm][fn] = mfma16(af[fm][kh], bfr[fn][kh], acc[fm][fn]);
    __builtin_amdgcn_s_setprio(0);
    // ---- phase 1: quadrant (1,0); new A1, reuse B0 ----
    for (int fm = 0; fm < 4; ++fm)
      for (int kh = 0; kh < 2; ++kh) RD_A(cur, 1, fm, kh, af[fm][kh]);
    if (pf) STAGE(t + 1, 2);
    __builtin_amdgcn_s_barrier();
    __builtin_amdgcn_s_setprio(1);
    for (int fm = 0; fm < 4; ++fm)
      for (int fn = 0; fn < 2; ++fn)
        for (int kh = 0; kh < 2; ++kh)
          acc[4 + fm][fn] = mfma16(af[fm][kh], bfr[fn][kh], acc[4 + fm][fn]);
    __builtin_amdgcn_s_setprio(0);
    // ---- phase 2: quadrant (1,1); new B1, reuse A1 ----
    for (int fn = 0; fn < 2; ++fn)
      for (int kh = 0; kh < 2; ++kh) RD_B(cur, 1, fn, kh, bfr[fn][kh]);
    if (pf) STAGE(t + 1, 3);
    __builtin_amdgcn_s_barrier();
    __builtin_amdgcn_s_setprio(1);
    for (int fm = 0; fm < 4; ++fm)
      for (int fn = 0; fn < 2; ++fn)
        for (int kh = 0; kh < 2; ++kh)
          acc[4 + fm][2 + fn] = mfma16(af[fm][kh], bfr[fn][kh], acc[4 + fm][2 + fn]);
    __builtin_amdgcn_s_setprio(0);
    // ---- phase 3: quadrant (0,1); re-read A0, reuse B1 ----
    for (int fm = 0; fm < 4; ++fm)
      for (int kh = 0; kh < 2; ++kh) RD_A(cur, 0, fm, kh, af[fm][kh]);
    __builtin_amdgcn_s_barrier();
    __builtin_amdgcn_s_setprio(1);
    for (int fm = 0; fm < 4; ++fm)
      for (int fn = 0; fn < 2; ++fn)
        for (int kh = 0; kh < 2; ++kh)
          acc[fm][2 + fn] = mfma16(af[fm][kh], bfr[fn][kh], acc[fm][2 + fn]);
    __builtin_amdgcn_s_setprio(0);
    // ---- tile boundary: next tile's LDS must be landed ----
    asm volatile("s_waitcnt vmcnt(0)" ::: "memory");
    __builtin_amdgcn_s_barrier();
  }
#undef STAGE
#undef RD_A
#undef RD_B

  for (int im = 0; im < 8; ++im)
    for (int in = 0; in < 4; ++in)
      for (int rr = 0; rr < 4; ++rr) {
        int row = row0 + wm * 128 + im * 16 + hi * 4 + rr;  // C/D: row=(l>>4)*4+r
        int col = col0 + wn * 64 + in * 16 + lo;            //      col=l&15
        store_out(&C[(size_t)row * N + col], acc[im][in][rr]);
      }
}

// ---------- RoPE in place on q,k regions of qkv ----------
__global__ __launch_bounds__(256) void rope_kernel(u16* __restrict__ qkv,
                                                   const float* __restrict__ cosb,
                                                   const float* __restrict__ sinb) {
  int idx = blockIdx.x * 256 + threadIdx.x;   // (m, head<40, d<64)
  int d = idx & 63;
  int head = (idx >> 6) % 40;
  int m = idx / (64 * 40);
  int s = m & (SEQ - 1);
  int col = head < 32 ? head * 128 : 4096 + (head - 32) * 128;
  u16* p = qkv + (size_t)m * NQKV + col;
  float x1 = bf2f(p[d]), x2 = bf2f(p[d + 64]);
  float c = cosb[s * 64 + d], sn = sinb[s * 64 + d];
  p[d] = f2bf(x1 * c - x2 * sn);
  p[d + 64] = f2bf(x2 * c + x1 * sn);
}

// ---------- V transpose: qkv v-region -> Vt[b][kvh][d][S] ----------
__global__ __launch_bounds__(256) void vtrans_kernel(const u16* __restrict__ qkv,
                                                     u16* __restrict__ Vt) {
  __shared__ u16 tile[32][33];
  int bid = blockIdx.x;
  int dt = bid & 3;
  int st = (bid >> 2) & 63;
  int bk = bid >> 8;               // b*8+kvh
  int b = bk >> 3, kvh = bk & 7;
  int tx = threadIdx.x & 31, ty = threadIdx.x >> 5;
  for (int i = 0; i < 4; ++i) {
    int s = st * 32 + ty + 8 * i;
    tile[ty + 8 * i][tx] = qkv[(size_t)(b * SEQ + s) * NQKV + 5120 + kvh * 128 + dt * 32 + tx];
  }
  __syncthreads();
  for (int i = 0; i < 4; ++i) {
    int d = dt * 32 + ty + 8 * i;
    Vt[((size_t)bk * 128 + d) * SEQ + st * 32 + tx] = tile[tx][ty + 8 * i];
  }
}

// ---------- flash attention: 4 waves/block, 32 q-rows/wave, KBLK=64 ----------
// R5 post-mortem: occupancy 11.3% — causal wedge load imbalance (block work
// ranges 1:16). Fix: COMPLEMENTARY-PAIR BALANCING — each block runs q-chunks
// {p, 15-p} sequentially: per-block work = 34 k-tiles, exactly uniform over
// all 512 blocks. Also: causal mask hoisted to wave-uniform diagonal branch;
// exp via exp2f with scale*log2e folded into one fma (scores in raw units).
__global__ __launch_bounds__(256) void flash_kernel(const u16* __restrict__ qkv,
                                                    const u16* __restrict__ Vt,
                                                    u16* __restrict__ attn) {
  const float C2 = 0.12751740f;  // (1/sqrt(128)) * log2(e)
  int bid = blockIdx.x;
  int bh = bid & 63;
  int pr = bid >> 6;               // pair index 0..7
  int h = bh & 31;
  int b = bh >> 5;
  int w = threadIdx.x >> 6, l = threadIdx.x & 63;
  int lo = l & 15, hi = l >> 4;
  int kvh = h >> 2;

  __shared__ __align__(16) u16 Ks[64 * 128];      // [row][chunk^=(row&7)] 16B chunks
  __shared__ __align__(16) u16 Vs[128 * 64];      // [d]  [chunk^=(d&7)]   16B chunks
  __shared__ __align__(16) u16 P_lds[4][32][72];  // per-wave P, padded rows
  u16(*P)[72] = P_lds[w];

  const u16* kb = qkv + (size_t)(b * SEQ) * NQKV + 4096 + kvh * 128;
  const u16* vtb = Vt + (size_t)(b * 8 + kvh) * 128 * SEQ;

  for (int pass = 0; pass < 2; ++pass) {
    int qc = pass ? 15 - pr : pr;
    int q0 = qc * 128 + w * 32;

    bf16x8 aq[2][4];
    for (int s2 = 0; s2 < 2; ++s2) {
      const u16* qr = qkv + (size_t)(b * SEQ + q0 + s2 * 16 + lo) * NQKV + h * 128 + hi * 8;
      for (int dk = 0; dk < 4; ++dk) aq[s2][dk] = *(const bf16x8*)(qr + dk * 32);
    }
    f32x4 o[2][8] = {};
    float mreg[2][4], lreg[2][4];
    for (int s2 = 0; s2 < 2; ++s2)
      for (int r = 0; r < 4; ++r) { mreg[s2][r] = -1e30f; lreg[s2][r] = 0.f; }

    int ktend = 2 * qc + 1;            // block-uniform k-loop
    int myktmax = 2 * qc + (w >> 1);   // this wave's causal limit

    for (int kt = 0; kt <= ktend; ++kt) {
      // ---- stage K tile: 64 rows x 256B; 16 wave-instrs, 4/wave ----
      for (int i = 0; i < 4; ++i) {
        int ck = w * 4 + i;
        int r = ck * 4 + (l >> 4);     // 4 rows per 1KB chunk, 16 lanes/row
        int c = l & 15;                // 16B chunk within row
        gload16(kb + (size_t)(kt * 64 + r) * NQKV + (size_t)((c ^ (r & 7)) * 8),
                &Ks[ck * 512]);
      }
      // ---- stage Vt tile: 128 rows x 128B; 16 wave-instrs, 4/wave ----
      for (int i = 0; i < 4; ++i) {
        int ck = w * 4 + i;
        int r = ck * 8 + (l >> 3);     // 8 rows per 1KB chunk, 8 lanes/row
        int c = l & 7;
        gload16(vtb + (size_t)r * SEQ + kt * 64 + ((c ^ (r & 7)) * 8),
                &Vs[ck * 512]);
      }
      __syncthreads();                 // drains vmcnt, tiles ready

      bool active = (kt <= myktmax);
      if (active) {
        // ---- scores: S = Q K^T (K from swizzled LDS), raw units ----
        f32x4 sc[2][4];
        for (int ct = 0; ct < 4; ++ct) {
          bf16x8 kf[4];
          int row = ct * 16 + lo;
          for (int dk = 0; dk < 4; ++dk)
            kf[dk] = *(const bf16x8*)&Ks[row * 128 + (((dk * 4 + hi) ^ (row & 7)) * 8)];
          for (int s2 = 0; s2 < 2; ++s2) {
            f32x4 a = {0.f, 0.f, 0.f, 0.f};
            for (int dk = 0; dk < 4; ++dk) a = mfma16(aq[s2][dk], kf[dk], a);
            sc[s2][ct] = a;
          }
        }
        // ---- causal mask: wave-uniform, diagonal tile only ----
        if (kt == myktmax) {
          for (int s2 = 0; s2 < 2; ++s2)
            for (int ct = 0; ct < 4; ++ct)
              for (int r = 0; r < 4; ++r)
                if (kt * 64 + ct * 16 + lo > q0 + s2 * 16 + hi * 4 + r)
                  sc[s2][ct][r] = -1e30f;
        }
        // ---- online softmax (exp2, fused scale) ----
        for (int s2 = 0; s2 < 2; ++s2) {
          float pv[4][4];
          float tm[4] = {-1e30f, -1e30f, -1e30f, -1e30f};
          for (int ct = 0; ct < 4; ++ct)
            for (int r = 0; r < 4; ++r) {
              pv[ct][r] = sc[s2][ct][r];
              tm[r] = fmaxf(tm[r], pv[ct][r]);
            }
          for (int r = 0; r < 4; ++r) {
            float t = tm[r];
            t = fmaxf(t, __shfl_xor(t, 1));
            t = fmaxf(t, __shfl_xor(t, 2));
            t = fmaxf(t, __shfl_xor(t, 4));
            t = fmaxf(t, __shfl_xor(t, 8));
            float mnew = fmaxf(mreg[s2][r], t);
            float alpha = exp2f((mreg[s2][r] - mnew) * C2);
            mreg[s2][r] = mnew;
            float mc = mnew * C2;
            float rs = 0.f;
            for (int ct = 0; ct < 4; ++ct) {
              float p = exp2f(__builtin_fmaf(pv[ct][r], C2, -mc));
              pv[ct][r] = p;
              rs += p;
            }
            rs += __shfl_xor(rs, 1);
            rs += __shfl_xor(rs, 2);
            rs += __shfl_xor(rs, 4);
            rs += __shfl_xor(rs, 8);
            lreg[s2][r] = lreg[s2][r] * alpha + rs;
            for (int dt = 0; dt < 8; ++dt) o[s2][dt][r] *= alpha;
            for (int ct = 0; ct < 4; ++ct)
              P[s2 * 16 + hi * 4 + r][ct * 16 + lo] = f2bf(pv[ct][r]);
          }
        }
        asm volatile("s_waitcnt lgkmcnt(0)" ::: "memory");  // P visible (per-wave)
        // ---- O += P V (V from swizzled LDS) ----
        for (int kk = 0; kk < 2; ++kk) {
          bf16x8 ap[2];
          for (int s2 = 0; s2 < 2; ++s2)
            ap[s2] = *(const bf16x8*)&P[s2 * 16 + lo][kk * 32 + hi * 8];
          for (int dt = 0; dt < 8; ++dt) {
            int row = dt * 16 + lo;
            bf16x8 vf = *(const bf16x8*)&Vs[row * 64 + (((kk * 4 + hi) ^ (row & 7)) * 8)];
            for (int s2 = 0; s2 < 2; ++s2) o[s2][dt] = mfma16(ap[s2], vf, o[s2][dt]);
          }
        }
      }
      __syncthreads();                 // all waves done before next stage
    }
    // ---- epilogue for this pass ----
    for (int s2 = 0; s2 < 2; ++s2)
      for (int dt = 0; dt < 8; ++dt)
        for (int r = 0; r < 4; ++r) {
          float v2 = o[s2][dt][r] / lreg[s2][r];
          attn[(size_t)(b * SEQ + q0 + s2 * 16 + hi * 4 + r) * 4096 + h * 128 + dt * 16 + lo] = f2bf(v2);
        }
  }
}

extern "C" void kernel_launch(void* const* d_in, const int* in_sizes, int n_in,
                              void* d_out, int out_size, void* d_ws, size_t ws_size,
                              hipStream_t stream) {
  const float* hidden = (const float*)d_in[0];
  const float* Wqkv = (const float*)d_in[1];
  const float* Wo = (const float*)d_in[2];
  const float* cosb = (const float*)d_in[3];
  const float* sinb = (const float*)d_in[4];
  // d_in[5] (attention_mask) is exactly causal triu(-1e9): applied analytically.
  float* out = (float*)d_out;

  char* ws = (char*)d_ws;
  u16* R1 = (u16*)ws;                  // 50,331,648 B : Wqkv_t, then attn
  u16* R2 = (u16*)(ws + 50331648);     // 50,331,648 B : qkv, then Wo_t
  u16* R3 = (u16*)(ws + 100663296);    // 33,554,432 B : hidden_bf16, then Vt
  // total 128 MiB

  // 1. hidden fp32 -> bf16
  conv_kernel<<<16384, 256, 0, stream>>>(hidden, R3);
  // 2. Wqkv [4096][6144] -> [6144][4096] bf16
  transconv_kernel<<<dim3(6144 / 32, 4096 / 32), 256, 0, stream>>>(Wqkv, R1, 4096, 6144);
  // 3. qkv = hidden x Wqkv (bf16 out); grid 384 = (4096/256)*(6144/256)
  gemm_kernel<u16><<<384, 512, 0, stream>>>(R3, R1, R2, 4096, 6144, 4096, 16);
  // 4. RoPE on q,k
  rope_kernel<<<40960, 256, 0, stream>>>(R2, cosb, sinb);
  // 5. V -> Vt[b][kvh][d][S]
  vtrans_kernel<<<4096, 256, 0, stream>>>(R2, R3);
  // 6. flash attention -> attn (bf16); 512 uniform-work blocks
  flash_kernel<<<512, 256, 0, stream>>>(R2, R3, R1);
  // 7. Wo [4096][4096] -> [4096][4096]^T bf16
  transconv_kernel<<<dim3(4096 / 32, 4096 / 32), 256, 0, stream>>>(Wo, R2, 4096, 4096);
  // 8. out = attn x Wo (fp32 out); grid 256 = (4096/256)*(4096/256)
  gemm_kernel<float><<<256, 512, 0, stream>>>(R1, R2, out, 4096, 4096, 4096, 16);
}

// Round 7
// 544.951 us; speedup vs baseline: 1.2679x; 1.2679x over previous
//
#include <hip/hip_runtime.h>

typedef unsigned short u16;
typedef __bf16 bf16x8 __attribute__((ext_vector_type(8)));
typedef float f32x4 __attribute__((ext_vector_type(4)));
typedef float f32x16 __attribute__((ext_vector_type(16)));
typedef u16 u16x4 __attribute__((ext_vector_type(4)));

#define SEQ 2048
#define NQKV 6144
#define HID 4096

__device__ inline u16 f2bf(float f) {
  union { float f; unsigned u; } x; x.f = f;
  unsigned r = x.u + 0x7fffu + ((x.u >> 16) & 1u);  // RNE
  return (u16)(r >> 16);
}
__device__ inline float bf2f(u16 u) {
  union { unsigned u; float f; } x; x.u = ((unsigned)u) << 16;
  return x.f;
}
__device__ inline f32x4 mfma16(bf16x8 a, bf16x8 b, f32x4 c) {
  return __builtin_amdgcn_mfma_f32_16x16x32_bf16(a, b, c, 0, 0, 0);
}
__device__ inline f32x16 mfma32(bf16x8 a, bf16x8 b, f32x16 c) {
  return __builtin_amdgcn_mfma_f32_32x32x16_bf16(a, b, c, 0, 0, 0);
}
__device__ inline unsigned cvtpk(float lo, float hi) {
  unsigned r;
  asm("v_cvt_pk_bf16_f32 %0, %1, %2" : "=v"(r) : "v"(lo), "v"(hi));
  return r;
}
__device__ inline void gload16(const void* g, void* l) {
  __builtin_amdgcn_global_load_lds((const __attribute__((address_space(1))) void*)g,
                                   (__attribute__((address_space(3))) void*)l,
                                   16, 0, 0);
}

// ---------- fp32 -> bf16 contiguous convert ----------
__global__ __launch_bounds__(256) void conv_kernel(const float* __restrict__ in,
                                                   u16* __restrict__ out) {
  int i = (blockIdx.x * 256 + threadIdx.x) * 4;
  float4 v = *(const float4*)(in + i);
  u16x4 o;
  o[0] = f2bf(v.x); o[1] = f2bf(v.y); o[2] = f2bf(v.z); o[3] = f2bf(v.w);
  *(u16x4*)(out + i) = o;
}

// ---------- fp32 [R][C] -> bf16 [C][R] transpose-convert ----------
__global__ __launch_bounds__(256) void transconv_kernel(const float* __restrict__ in,
                                                        u16* __restrict__ out,
                                                        int R, int C) {
  __shared__ u16 tile[32][33];
  int c0 = blockIdx.x * 32, r0 = blockIdx.y * 32;
  int tx = threadIdx.x & 31, ty = threadIdx.x >> 5;
  for (int i = 0; i < 4; ++i)
    tile[ty + 8 * i][tx] = f2bf(in[(size_t)(r0 + ty + 8 * i) * C + c0 + tx]);
  __syncthreads();
  for (int i = 0; i < 4; ++i)
    out[(size_t)(c0 + ty + 8 * i) * R + r0 + tx] = tile[tx][ty + 8 * i];
}

// ---------- bf16 GEMM: A[M][K] x Bt[N][K] -> C[M][N] ----------
// 256x256/BK64 8-wave quadrant schedule (R5). Unchanged this round.
__device__ inline void store_out(u16* p, float v) { *p = f2bf(v); }
__device__ inline void store_out(float* p, float v) { *p = v; }

template <typename OutT>
__global__ __launch_bounds__(512, 2) void gemm_kernel(const u16* __restrict__ A,
                                                      const u16* __restrict__ Bt,
                                                      OutT* __restrict__ C,
                                                      int M, int N, int K, int nby) {
  __shared__ __align__(16) u16 As[2][256 * 64];
  __shared__ __align__(16) u16 Bs[2][256 * 64];
  int nwg = gridDim.x;                      // multiple of 8
  int bid = blockIdx.x;
  int s = (bid & 7) * (nwg >> 3) + (bid >> 3);   // XCD-contiguous, bijective
  int by = s % nby, bx = s / nby;
  int row0 = by * 256, col0 = bx * 256;
  int tid = threadIdx.x, w = tid >> 6, l = tid & 63;
  int wm = w >> 2, wn = w & 3;              // wave tile 128x64
  int lo = l & 15, hi = l >> 4;
  int lr = l >> 3;                          // staging: row within 8-row chunk
  int lc = (l & 7) ^ ((l >> 3) & 7);        // pre-swizzled source k-chunk
  const u16* Ab = A + (size_t)row0 * K;
  const u16* Bb = Bt + (size_t)col0 * K;
  int nkt = K >> 6;

  f32x4 acc[8][4] = {};

#define STAGE(tt, g)                                                          \
  { int ci = (g) * 8 + w;                                                     \
    gload16(Ab + (size_t)(ci * 8 + lr) * K + (tt) * 64 + lc * 8,              \
            &As[(tt) & 1][ci * 512]);                                         \
    gload16(Bb + (size_t)(ci * 8 + lr) * K + (tt) * 64 + lc * 8,              \
            &Bs[(tt) & 1][ci * 512]); }
#define RD_A(cur, qm, fm, kh, dst)                                            \
  { int r = wm * 128 + (qm) * 64 + (fm) * 16 + lo;                            \
    dst = *(const bf16x8*)&As[cur][r * 64 + ((((kh) * 4 + hi) ^ (r & 7)) * 8)]; }
#define RD_B(cur, qn, fn, kh, dst)                                            \
  { int r = wn * 64 + (qn) * 32 + (fn) * 16 + lo;                             \
    dst = *(const bf16x8*)&Bs[cur][r * 64 + ((((kh) * 4 + hi) ^ (r & 7)) * 8)]; }

  // prologue: stage tile 0 fully
  STAGE(0, 0); STAGE(0, 1); STAGE(0, 2); STAGE(0, 3);
  asm volatile("s_waitcnt vmcnt(0)" ::: "memory");
  __builtin_amdgcn_s_barrier();

  bf16x8 af[4][2], bfr[2][2];
  for (int t = 0; t < nkt; ++t) {
    int cur = t & 1;
    bool pf = (t + 1 < nkt);
    // ---- phase 0: quadrant (qm=0, qn=0); load A0, B0 ----
    for (int fm = 0; fm < 4; ++fm)
      for (int kh = 0; kh < 2; ++kh) RD_A(cur, 0, fm, kh, af[fm][kh]);
    for (int fn = 0; fn < 2; ++fn)
      for (int kh = 0; kh < 2; ++kh) RD_B(cur, 0, fn, kh, bfr[fn][kh]);
    if (pf) { STAGE(t + 1, 0); STAGE(t + 1, 1); }
    __builtin_amdgcn_s_barrier();
    __builtin_amdgcn_s_setprio(1);
    for (int fm = 0; fm < 4; ++fm)
      for (int fn = 0; fn < 2; ++fn)
        for (int kh = 0; kh < 2; ++kh)
          acc[fm][fn] = mfma16(af[fm][kh], bfr[fn][kh], acc[fm][fn]);
    __builtin_amdgcn_s_setprio(0);
    // ---- phase 1: quadrant (1,0); new A1, reuse B0 ----
    for (int fm = 0; fm < 4; ++fm)
      for (int kh = 0; kh < 2; ++kh) RD_A(cur, 1, fm, kh, af[fm][kh]);
    if (pf) STAGE(t + 1, 2);
    __builtin_amdgcn_s_barrier();
    __builtin_amdgcn_s_setprio(1);
    for (int fm = 0; fm < 4; ++fm)
      for (int fn = 0; fn < 2; ++fn)
        for (int kh = 0; kh < 2; ++kh)
          acc[4 + fm][fn] = mfma16(af[fm][kh], bfr[fn][kh], acc[4 + fm][fn]);
    __builtin_amdgcn_s_setprio(0);
    // ---- phase 2: quadrant (1,1); new B1, reuse A1 ----
    for (int fn = 0; fn < 2; ++fn)
      for (int kh = 0; kh < 2; ++kh) RD_B(cur, 1, fn, kh, bfr[fn][kh]);
    if (pf) STAGE(t + 1, 3);
    __builtin_amdgcn_s_barrier();
    __builtin_amdgcn_s_setprio(1);
    for (int fm = 0; fm < 4; ++fm)
      for (int fn = 0; fn < 2; ++fn)
        for (int kh = 0; kh < 2; ++kh)
          acc[4 + fm][2 + fn] = mfma16(af[fm][kh], bfr[fn][kh], acc[4 + fm][2 + fn]);
    __builtin_amdgcn_s_setprio(0);
    // ---- phase 3: quadrant (0,1); re-read A0, reuse B1 ----
    for (int fm = 0; fm < 4; ++fm)
      for (int kh = 0; kh < 2; ++kh) RD_A(cur, 0, fm, kh, af[fm][kh]);
    __builtin_amdgcn_s_barrier();
    __builtin_amdgcn_s_setprio(1);
    for (int fm = 0; fm < 4; ++fm)
      for (int fn = 0; fn < 2; ++fn)
        for (int kh = 0; kh < 2; ++kh)
          acc[fm][2 + fn] = mfma16(af[fm][kh], bfr[fn][kh], acc[fm][2 + fn]);
    __builtin_amdgcn_s_setprio(0);
    // ---- tile boundary: next tile's LDS must be landed ----
    asm volatile("s_waitcnt vmcnt(0)" ::: "memory");
    __builtin_amdgcn_s_barrier();
  }
#undef STAGE
#undef RD_A
#undef RD_B

  for (int im = 0; im < 8; ++im)
    for (int in = 0; in < 4; ++in)
      for (int rr = 0; rr < 4; ++rr) {
        int row = row0 + wm * 128 + im * 16 + hi * 4 + rr;  // C/D: row=(l>>4)*4+r
        int col = col0 + wn * 64 + in * 16 + lo;            //      col=l&15
        store_out(&C[(size_t)row * N + col], acc[im][in][rr]);
      }
}

// ---------- RoPE in place on q,k regions of qkv ----------
__global__ __launch_bounds__(256) void rope_kernel(u16* __restrict__ qkv,
                                                   const float* __restrict__ cosb,
                                                   const float* __restrict__ sinb) {
  int idx = blockIdx.x * 256 + threadIdx.x;   // (m, head<40, d<64)
  int d = idx & 63;
  int head = (idx >> 6) % 40;
  int m = idx / (64 * 40);
  int s = m & (SEQ - 1);
  int col = head < 32 ? head * 128 : 4096 + (head - 32) * 128;
  u16* p = qkv + (size_t)m * NQKV + col;
  float x1 = bf2f(p[d]), x2 = bf2f(p[d + 64]);
  float c = cosb[s * 64 + d], sn = sinb[s * 64 + d];
  p[d] = f2bf(x1 * c - x2 * sn);
  p[d + 64] = f2bf(x2 * c + x1 * sn);
}

// ---------- V transpose: qkv v-region -> Vt[b][kvh][d][S] ----------
__global__ __launch_bounds__(256) void vtrans_kernel(const u16* __restrict__ qkv,
                                                     u16* __restrict__ Vt) {
  __shared__ u16 tile[32][33];
  int bid = blockIdx.x;
  int dt = bid & 3;
  int st = (bid >> 2) & 63;
  int bk = bid >> 8;               // b*8+kvh
  int b = bk >> 3, kvh = bk & 7;
  int tx = threadIdx.x & 31, ty = threadIdx.x >> 5;
  for (int i = 0; i < 4; ++i) {
    int s = st * 32 + ty + 8 * i;
    tile[ty + 8 * i][tx] = qkv[(size_t)(b * SEQ + s) * NQKV + 5120 + kvh * 128 + dt * 32 + tx];
  }
  __syncthreads();
  for (int i = 0; i < 4; ++i) {
    int d = dt * 32 + ty + 8 * i;
    Vt[((size_t)bk * 128 + d) * SEQ + st * 32 + tx] = tile[tx][ty + 8 * i];
  }
}

// ---------- flash attention: swapped-QK in-register softmax (guide SB) ----------
// R6 post-mortem: limiter was LDS/cross-lane pipe (64 shfl + 36 P-LDS ops per
// wave-tile) + per-tile exposed staging latency (syncthreads drains vmcnt 0).
// Rewrite: 32x32x16 MFMA, S = mfma(K,Q) -> lane owns one q-row (col=lane&31,
// row=crow(r,hi)); softmax = in-lane tree + ONE shfl_xor(32). P->A-frag via
// 16 cvt_pk + 8 shfl_xor(32) half-exchange. PV swapped (O^T = mfma(Vt,P)) so
// m/l/alpha stay lane-local. K/V LDS double-buffered, counted vmcnt(8), raw
// s_barrier (T3-lite). T13 defer-max (THR=8 exp2-units). P_lds eliminated.
__global__ __launch_bounds__(256, 2) void flash_kernel(const u16* __restrict__ qkv,
                                                       const u16* __restrict__ Vt,
                                                       u16* __restrict__ attn) {
  const float C2 = 0.12751740f;  // (1/sqrt(128)) * log2(e)
  int bid = blockIdx.x;
  int bh = bid & 63;
  int pr = bid >> 6;               // pair index 0..7 -> chunks {pr, 15-pr}
  int h = bh & 31;
  int b = bh >> 5;
  int w = threadIdx.x >> 6, l = threadIdx.x & 63;
  int hv = l >> 5;                 // lane half (0/1)
  int q32 = l & 31;                // q column within wave tile
  int kvh = h >> 2;

  __shared__ __align__(16) u16 Ks[2][64 * 128];   // [buf][krow][d], swizzled 16B chunks
  __shared__ __align__(16) u16 Vs[2][128 * 64];   // [buf][drow][k], swizzled 16B chunks

  const u16* kb = qkv + (size_t)(b * SEQ) * NQKV + 4096 + kvh * 128;
  const u16* vtb = Vt + (size_t)(b * 8 + kvh) * 128 * SEQ;

#define STAGEKV(TT, BF)                                                       \
  { _Pragma("unroll")                                                         \
    for (int i = 0; i < 4; ++i) {                                             \
      int ck = w * 4 + i;                                                     \
      int rk = ck * 4 + (l >> 4);                                             \
      gload16(kb + (size_t)((TT) * 64 + rk) * NQKV + (((l & 15) ^ (rk & 7)) * 8), \
              &Ks[BF][ck * 512]);                                             \
      int rv = ck * 8 + (l >> 3);                                             \
      gload16(vtb + (size_t)rv * SEQ + (TT) * 64 + (((l & 7) ^ (rv & 7)) * 8), \
              &Vs[BF][ck * 512]);                                             \
    } }

  for (int pass = 0; pass < 2; ++pass) {
    int qc = pass ? 15 - pr : pr;
    int q0 = qc * 128 + w * 32;
    int qg = q0 + q32;             // this lane's q-row (global within batch seq)
    __syncthreads();               // protect LDS reuse across passes

    // Q fragments: lane holds Q[qg][d0*16 + hv*8 + j]
    bf16x8 qf[8];
    {
      const u16* qr = qkv + (size_t)(b * SEQ + qg) * NQKV + h * 128 + hv * 8;
#pragma unroll
      for (int d0 = 0; d0 < 8; ++d0) qf[d0] = *(const bf16x8*)(qr + d0 * 16);
    }
    f32x16 o[4] = {};              // O^T: lane holds [d=db*32+crow(r,hv)][q=qg]
    float mreg = -1e30f, lreg = 0.f;
    int ktend = 2 * qc + 1;
    int mykt = 2 * qc + (w >> 1);  // wave's causal limit

    STAGEKV(0, 0);
    for (int kt = 0; kt <= ktend; ++kt) {
      int buf = kt & 1;
      if (kt < ktend) {
        STAGEKV(kt + 1, buf ^ 1);
        asm volatile("s_waitcnt vmcnt(8)" ::: "memory");  // tile kt landed
      } else {
        asm volatile("s_waitcnt vmcnt(0)" ::: "memory");
      }
      __builtin_amdgcn_s_barrier();

      if (kt <= mykt) {
        // ---- S = K Q^T: lane -> S[k=crow(r,hv)(+32)][q=qg] ----
        f32x16 s0 = {}, s1 = {};
        int swzk = q32 & 7;
#pragma unroll
        for (int d0 = 0; d0 < 8; ++d0) {
          int sl = (((d0 * 2 + hv) ^ swzk) * 8);
          bf16x8 k0 = *(const bf16x8*)&Ks[buf][q32 * 128 + sl];
          bf16x8 k1 = *(const bf16x8*)&Ks[buf][(32 + q32) * 128 + sl];
          s0 = mfma32(k0, qf[d0], s0);
          s1 = mfma32(k1, qf[d0], s1);
        }
        // ---- causal mask (diagonal tile only, wave-uniform branch) ----
        if (kt == mykt) {
#pragma unroll
          for (int r = 0; r < 16; ++r) {
            int kloc = (r & 3) + 8 * (r >> 2) + 4 * hv;
            if (kt * 64 + kloc > qg) s0[r] = -1e30f;
            if (kt * 64 + 32 + kloc > qg) s1[r] = -1e30f;
          }
        }
        // ---- in-register online softmax (one q-row per lane) ----
        float pm = -1e30f;
#pragma unroll
        for (int r = 0; r < 16; ++r) {
          pm = fmaxf(pm, s0[r]);
          pm = fmaxf(pm, s1[r]);
        }
        pm = fmaxf(pm, __shfl_xor(pm, 32));
        if (!__all(pm - mreg <= 62.746f)) {   // defer-max, THR=8 exp2-units
          float mnew = fmaxf(mreg, pm);
          float al = exp2f((mreg - mnew) * C2);
          lreg *= al;
#pragma unroll
          for (int r = 0; r < 16; ++r) {
            o[0][r] *= al; o[1][r] *= al; o[2][r] *= al; o[3][r] *= al;
          }
          mreg = mnew;
        }
        float rs = 0.f;
#pragma unroll
        for (int r = 0; r < 16; ++r) {
          s0[r] = exp2f((s0[r] - mreg) * C2); rs += s0[r];
          s1[r] = exp2f((s1[r] - mreg) * C2); rs += s1[r];
        }
        rs += __shfl_xor(rs, 32);
        lreg += rs;
        // ---- P -> bf16 A/B fragments: cvt_pk + half-exchange ----
        // pa[ks]: lane holds P[q=qg][k = ks*16 + hv*8 + j]
        bf16x8 pa[4];
#define MKPA(KSI, SP, RB)                                                     \
        { unsigned wA = cvtpk(SP[(RB) + 0], SP[(RB) + 1]);                    \
          unsigned wB = cvtpk(SP[(RB) + 2], SP[(RB) + 3]);                    \
          unsigned wC = cvtpk(SP[(RB) + 4], SP[(RB) + 5]);                    \
          unsigned wD = cvtpk(SP[(RB) + 6], SP[(RB) + 7]);                    \
          unsigned sA = __shfl_xor(wA, 32), sB = __shfl_xor(wB, 32);          \
          unsigned sC = __shfl_xor(wC, 32), sD = __shfl_xor(wD, 32);          \
          union { unsigned u[4]; bf16x8 v; } pk;                              \
          pk.u[0] = hv ? sC : wA; pk.u[1] = hv ? sD : wB;                     \
          pk.u[2] = hv ? wC : sA; pk.u[3] = hv ? wD : sB;                     \
          pa[KSI] = pk.v; }
        MKPA(0, s0, 0) MKPA(1, s0, 8) MKPA(2, s1, 0) MKPA(3, s1, 8)
#undef MKPA
        // ---- O^T += Vt P  (keeps q lane-local) ----
#pragma unroll
        for (int db = 0; db < 4; ++db) {
          int rv = db * 32 + q32;
          int swz = rv & 7;
#pragma unroll
          for (int ks = 0; ks < 4; ++ks) {
            bf16x8 vf = *(const bf16x8*)&Vs[buf][rv * 64 + (((ks * 2 + hv) ^ swz) * 8)];
            o[db] = mfma32(vf, pa[ks], o[db]);
          }
        }
      }
    }
    // ---- epilogue: lane owns row qg; packed 8B stores ----
    float invl = 1.0f / lreg;
    u16* op = attn + (size_t)(b * SEQ + qg) * 4096 + h * 128 + hv * 4;
#pragma unroll
    for (int db = 0; db < 4; ++db)
#pragma unroll
      for (int g = 0; g < 4; ++g) {
        // elements r=g*4+i -> d = db*32 + 8g + 4hv + i
        unsigned w0 = cvtpk(o[db][g * 4 + 0] * invl, o[db][g * 4 + 1] * invl);
        unsigned w1 = cvtpk(o[db][g * 4 + 2] * invl, o[db][g * 4 + 3] * invl);
        uint2 val; val.x = w0; val.y = w1;
        *(uint2*)(op + db * 32 + g * 8) = val;
      }
  }
#undef STAGEKV
}

extern "C" void kernel_launch(void* const* d_in, const int* in_sizes, int n_in,
                              void* d_out, int out_size, void* d_ws, size_t ws_size,
                              hipStream_t stream) {
  const float* hidden = (const float*)d_in[0];
  const float* Wqkv = (const float*)d_in[1];
  const float* Wo = (const float*)d_in[2];
  const float* cosb = (const float*)d_in[3];
  const float* sinb = (const float*)d_in[4];
  // d_in[5] (attention_mask) is exactly causal triu(-1e9): applied analytically.
  float* out = (float*)d_out;

  char* ws = (char*)d_ws;
  u16* R1 = (u16*)ws;                  // 50,331,648 B : Wqkv_t, then attn
  u16* R2 = (u16*)(ws + 50331648);     // 50,331,648 B : qkv, then Wo_t
  u16* R3 = (u16*)(ws + 100663296);    // 33,554,432 B : hidden_bf16, then Vt
  // total 128 MiB

  // 1. hidden fp32 -> bf16
  conv_kernel<<<16384, 256, 0, stream>>>(hidden, R3);
  // 2. Wqkv [4096][6144] -> [6144][4096] bf16
  transconv_kernel<<<dim3(6144 / 32, 4096 / 32), 256, 0, stream>>>(Wqkv, R1, 4096, 6144);
  // 3. qkv = hidden x Wqkv (bf16 out); grid 384 = (4096/256)*(6144/256)
  gemm_kernel<u16><<<384, 512, 0, stream>>>(R3, R1, R2, 4096, 6144, 4096, 16);
  // 4. RoPE on q,k
  rope_kernel<<<40960, 256, 0, stream>>>(R2, cosb, sinb);
  // 5. V -> Vt[b][kvh][d][S]
  vtrans_kernel<<<4096, 256, 0, stream>>>(R2, R3);
  // 6. flash attention -> attn (bf16); 512 uniform-work blocks
  flash_kernel<<<512, 256, 0, stream>>>(R2, R3, R1);
  // 7. Wo [4096][4096] -> [4096][4096]^T bf16
  transconv_kernel<<<dim3(4096 / 32, 4096 / 32), 256, 0, stream>>>(Wo, R2, 4096, 4096);
  // 8. out = attn x Wo (fp32 out); grid 256 = (4096/256)*(4096/256)
  gemm_kernel<float><<<256, 512, 0, stream>>>(R1, R2, out, 4096, 4096, 4096, 16);
}